// Round 1
// 111.092 us; speedup vs baseline: 1.0108x; 1.0108x over previous
//
#include <hip/hip_runtime.h>

#define NB   4
#define CO   16
#define PH   7
#define PW   7
#define SR   2
#define HH   80
#define WW   80
#define NROI 512
#define CIJ  (CO*PH*PW)   // 784
#define PLANE (HH*WW)     // 6400 floats = 25.6 KB
#define NF4  (PLANE/4)    // 1600

typedef float f4v __attribute__((ext_vector_type(4), aligned(16)));

// Process one ROI slot against the LDS-staged plane for this block's (b, cij).
// All arguments are scalars/registers -> no scratch arrays (rule: no
// runtime-indexed local arrays).
__device__ __forceinline__ void psroi_one(
    const float* __restrict__ sp,
    float rb, float rx1, float ry1, float rx2, float ry2,
    int b, int i, int j, int cij, int m, float* __restrict__ out)
{
    if ((int)rb != b) return;

    float x1 = rx1 * (float)WW;
    float y1 = ry1 * (float)HH;
    float bin_w = fmaxf(rx2 * (float)WW - x1, 0.1f) * (1.0f / PW);
    float bin_h = fmaxf(ry2 * (float)HH - y1, 0.1f) * (1.0f / PH);

    float acc = 0.0f;
    #pragma unroll
    for (int sy = 0; sy < SR; ++sy) {
        float ys = y1 + (float)i * bin_h + ((float)sy + 0.5f) * bin_h * (1.0f / SR);
        bool ymask = (ys >= -1.0f) && (ys <= (float)HH);
        float yc = fminf(fmaxf(ys, 0.0f), (float)(HH - 1));
        int   y0 = (int)floorf(yc);
        int   y1i = min(y0 + 1, HH - 1);
        float ly = yc - (float)y0, hy = 1.0f - ly;
        #pragma unroll
        for (int sx = 0; sx < SR; ++sx) {
            float xs = x1 + (float)j * bin_w + ((float)sx + 0.5f) * bin_w * (1.0f / SR);
            bool xmask = (xs >= -1.0f) && (xs <= (float)WW);
            float xc = fminf(fmaxf(xs, 0.0f), (float)(WW - 1));
            int   x0 = (int)floorf(xc);
            int   x0c = min(x0, WW - 2);   // x0==79 -> lx==0, shifted pair exact
            bool  sh = (x0 != x0c);
            float lx = xc - (float)x0, hx = 1.0f - lx;

            float t0 = sp[y0  * WW + x0c], t1 = sp[y0  * WW + x0c + 1];
            float b0 = sp[y1i * WW + x0c], b1 = sp[y1i * WW + x0c + 1];

            float v00 = sh ? t1 : t0;
            float v10 = sh ? b1 : b0;
            float v = (v00 * hx + t1 * lx) * hy + (v10 * hx + b1 * lx) * ly;
            if (ymask && xmask) acc += v;
        }
    }
    out[(size_t)m * CIJ + cij] = acc * 0.25f;
}

// One block per (cij, b): stage the 25.6 KB plane to LDS (coalesced f4),
// load this thread's 2 ROI slots while staging is in flight (hidden under
// HBM latency), one barrier, then gather. No prep kernel, no workspace,
// no inter-kernel dependency. Global feat traffic = 80 MB (each plane once).
__global__ __launch_bounds__(256) void psroi_main_kernel(
    const float* __restrict__ feat,   // [B, CIJ, H, W]
    const float* __restrict__ rois,   // [N, 5]
    float* __restrict__ out)          // [N, CO, PH, PW]
{
    __shared__ __align__(16) float sp[PLANE];

    int u   = blockIdx.x;       // cij*4 + b
    int cij = u >> 2;
    int b   = u & 3;
    int rem = cij % (PH * PW);
    int i = rem / PW;
    int j = rem % PW;
    int n = threadIdx.x;

    // stage plane (b, cij): 1600 float4s with 256 threads
    const f4v* src = (const f4v*)(feat + ((size_t)b * CIJ + (size_t)cij) * PLANE);
    f4v* dst = (f4v*)sp;
    #pragma unroll
    for (int it = 0; it < 6; ++it)
        dst[it * 256 + n] = src[it * 256 + n];
    {
        int e = 1536 + n;
        if (e < NF4) dst[e] = src[e];
    }

    // ROI slots n and n+256, read while the plane loads are outstanding
    // (10 KB total per block, L2-resident after the first touch).
    const float* rp0 = rois + (size_t)n * 5;
    const float* rp1 = rois + ((size_t)n + 256) * 5;
    float a0 = rp0[0], a1 = rp0[1], a2 = rp0[2], a3 = rp0[3], a4 = rp0[4];
    float c0 = rp1[0], c1 = rp1[1], c2 = rp1[2], c3 = rp1[3], c4 = rp1[4];

    __syncthreads();

    psroi_one(sp, a0, a1, a2, a3, a4, b, i, j, cij, n,       out);
    psroi_one(sp, c0, c1, c2, c3, c4, b, i, j, cij, n + 256, out);
}

extern "C" void kernel_launch(void* const* d_in, const int* in_sizes, int n_in,
                              void* d_out, int out_size, void* d_ws, size_t ws_size,
                              hipStream_t stream)
{
    const float* feat = (const float*)d_in[0];
    const float* rois = (const float*)d_in[1];
    float* out = (float*)d_out;
    (void)d_ws; (void)ws_size; (void)in_sizes; (void)n_in; (void)out_size;

    psroi_main_kernel<<<CIJ * NB, 256, 0, stream>>>(feat, rois, out);
}